// Round 2
// baseline (111.960 us; speedup 1.0000x reference)
//
#include <hip/hip_runtime.h>

// AffinityLoss: per (b,c) channel (2048 of them, hw=16384):
//   cos^2 = (s.t)^2 / ((s.s)(t.t));  per_channel = sqrt(max(2-2cos^2,0))/hw
//   out = mean_b sum_c per_channel   (scalar)
// Memory-bound: 256 MiB fp32 streamed once. Round 1 hit 44.5us (~96% of the
// 42.6us HBM floor). This round fuses the final 2048-element reduction into
// the last-arriving block (atomic ticket + device fences) to drop the second
// dispatch (~2us). Ticket zeroed each call by a 4-byte memset node.

#define HW_ELEMS 16384
#define NBLOCKS  2048   // B*C = 8*256
#define NTHREADS 256
#define INV_B    0.125f

__global__ __launch_bounds__(NTHREADS)
void affinity_fused(const float* __restrict__ s,
                    const float* __restrict__ t,
                    float* __restrict__ partial,
                    unsigned int* __restrict__ ticket,
                    float* __restrict__ out) {
    const int bc  = blockIdx.x;
    const int tid = threadIdx.x;
    const float4* sp = reinterpret_cast<const float4*>(s + (size_t)bc * HW_ELEMS);
    const float4* tp = reinterpret_cast<const float4*>(t + (size_t)bc * HW_ELEMS);

    float ss = 0.f, tt = 0.f, st = 0.f;
    #pragma unroll
    for (int i = 0; i < HW_ELEMS / 4 / NTHREADS; ++i) {   // 16 float4 per input
        float4 a = sp[i * NTHREADS + tid];
        float4 b = tp[i * NTHREADS + tid];
        ss += a.x * a.x + a.y * a.y + a.z * a.z + a.w * a.w;
        tt += b.x * b.x + b.y * b.y + b.z * b.z + b.w * b.w;
        st += a.x * b.x + a.y * b.y + a.z * b.z + a.w * b.w;
    }

    // wave-64 butterfly reduce
    #pragma unroll
    for (int off = 32; off > 0; off >>= 1) {
        ss += __shfl_down(ss, off);
        tt += __shfl_down(tt, off);
        st += __shfl_down(st, off);
    }

    __shared__ float red[3][4];
    __shared__ bool  is_last;
    const int wave = tid >> 6;
    if ((tid & 63) == 0) {
        red[0][wave] = ss;
        red[1][wave] = tt;
        red[2][wave] = st;
    }
    __syncthreads();

    if (tid == 0) {
        float SS = red[0][0] + red[0][1] + red[0][2] + red[0][3];
        float TT = red[1][0] + red[1][1] + red[1][2] + red[1][3];
        float ST = red[2][0] + red[2][1] + red[2][2] + red[2][3];
        float cos2 = (ST * ST) / (SS * TT);
        partial[bc] = sqrtf(fmaxf(2.0f - 2.0f * cos2, 0.0f)) * (1.0f / (float)HW_ELEMS);
        __threadfence();                                  // publish partial[bc]
        unsigned int prev = atomicAdd(ticket, 1u);        // device-scope
        is_last = (prev == NBLOCKS - 1);
    }
    __syncthreads();
    if (!is_last) return;

    // Last block: all 2048 partials are published. Fixed-order deterministic sum.
    __threadfence();                                      // acquire
    float sum = 0.f;
    #pragma unroll
    for (int i = 0; i < NBLOCKS / NTHREADS; ++i)          // 8 per thread
        sum += partial[i * NTHREADS + tid];

    #pragma unroll
    for (int off = 32; off > 0; off >>= 1)
        sum += __shfl_down(sum, off);

    __shared__ float red2[4];
    if ((tid & 63) == 0) red2[tid >> 6] = sum;
    __syncthreads();
    if (tid == 0)
        out[0] = (red2[0] + red2[1] + red2[2] + red2[3]) * INV_B;
}

extern "C" void kernel_launch(void* const* d_in, const int* in_sizes, int n_in,
                              void* d_out, int out_size, void* d_ws, size_t ws_size,
                              hipStream_t stream) {
    const float* student = (const float*)d_in[0];
    const float* teacher = (const float*)d_in[1];
    float* out = (float*)d_out;
    float* partial       = (float*)d_ws;                      // 2048 floats
    unsigned int* ticket = (unsigned int*)((char*)d_ws + NBLOCKS * sizeof(float));

    hipMemsetAsync(ticket, 0, sizeof(unsigned int), stream);  // graph-capturable
    affinity_fused<<<NBLOCKS, NTHREADS, 0, stream>>>(student, teacher, partial,
                                                     ticket, out);
}

// Round 3
// 44.385 us; speedup vs baseline: 2.5224x; 2.5224x over previous
//
#include <hip/hip_runtime.h>

// AffinityLoss: for each (b,c) of [8,256] channels with hw=16384 spatial elems:
//   ss = s.s, tt = t.t, st = s.t  ->  cos^2 = st^2/(ss*tt)
//   per_channel = sqrt(max(2 - 2*cos^2, 0)) / hw
// out = mean_b( sum_c per_channel )  (scalar)
//
// Memory-bound: 256 MiB fp32 streamed once; HBM floor ~42.6us at 6.3 TB/s.
// Round 1 (this structure) measured 44.5us = ~96% of floor.
// Round 2 tried fusing the final reduce via atomic ticket + __threadfence():
// REGRESSED 44.5 -> 112us. Device-scope fences force per-XCD L2
// writeback/invalidate, destroying the L2/L3 residency that delivers the
// last ~2x of effective bandwidth. Keep the two-dispatch structure: a tiny
// second graph node (~2us) is far cheaper than device-scope coherence.

#define HW_ELEMS 16384
#define NBLOCKS  2048   // B*C = 8*256
#define NTHREADS 256
#define INV_B    0.125f

__global__ __launch_bounds__(NTHREADS)
void affinity_partial(const float* __restrict__ s,
                      const float* __restrict__ t,
                      float* __restrict__ partial) {
    const int bc  = blockIdx.x;
    const int tid = threadIdx.x;
    const float4* sp = reinterpret_cast<const float4*>(s + (size_t)bc * HW_ELEMS);
    const float4* tp = reinterpret_cast<const float4*>(t + (size_t)bc * HW_ELEMS);

    float ss = 0.f, tt = 0.f, st = 0.f;
    #pragma unroll
    for (int i = 0; i < HW_ELEMS / 4 / NTHREADS; ++i) {   // 16 float4 per thread
        float4 a = sp[i * NTHREADS + tid];
        float4 b = tp[i * NTHREADS + tid];
        ss += a.x * a.x + a.y * a.y + a.z * a.z + a.w * a.w;
        tt += b.x * b.x + b.y * b.y + b.z * b.z + b.w * b.w;
        st += a.x * b.x + a.y * b.y + a.z * b.z + a.w * b.w;
    }

    // wave-64 butterfly reduce
    #pragma unroll
    for (int off = 32; off > 0; off >>= 1) {
        ss += __shfl_down(ss, off);
        tt += __shfl_down(tt, off);
        st += __shfl_down(st, off);
    }

    __shared__ float red[3][4];
    const int wave = tid >> 6;
    if ((tid & 63) == 0) {
        red[0][wave] = ss;
        red[1][wave] = tt;
        red[2][wave] = st;
    }
    __syncthreads();

    if (tid == 0) {
        float SS = red[0][0] + red[0][1] + red[0][2] + red[0][3];
        float TT = red[1][0] + red[1][1] + red[1][2] + red[1][3];
        float ST = red[2][0] + red[2][1] + red[2][2] + red[2][3];
        float cos2 = (ST * ST) / (SS * TT);
        float v = sqrtf(fmaxf(2.0f - 2.0f * cos2, 0.0f)) * (1.0f / (float)HW_ELEMS);
        partial[bc] = v;
    }
}

__global__ __launch_bounds__(NTHREADS)
void affinity_final(const float* __restrict__ partial, float* __restrict__ out) {
    const int tid = threadIdx.x;
    float sum = 0.f;
    #pragma unroll
    for (int i = 0; i < NBLOCKS / NTHREADS; ++i)   // 8 iters
        sum += partial[i * NTHREADS + tid];

    #pragma unroll
    for (int off = 32; off > 0; off >>= 1)
        sum += __shfl_down(sum, off);

    __shared__ float red[4];
    if ((tid & 63) == 0) red[tid >> 6] = sum;
    __syncthreads();
    if (tid == 0)
        out[0] = (red[0] + red[1] + red[2] + red[3]) * INV_B;
}

extern "C" void kernel_launch(void* const* d_in, const int* in_sizes, int n_in,
                              void* d_out, int out_size, void* d_ws, size_t ws_size,
                              hipStream_t stream) {
    const float* student = (const float*)d_in[0];
    const float* teacher = (const float*)d_in[1];
    float* out = (float*)d_out;
    float* partial = (float*)d_ws;   // 2048 floats = 8 KiB scratch

    affinity_partial<<<NBLOCKS, NTHREADS, 0, stream>>>(student, teacher, partial);
    affinity_final<<<1, NTHREADS, 0, stream>>>(partial, out);
}